// Round 1
// baseline (511.959 us; speedup 1.0000x reference)
//
#include <hip/hip_runtime.h>

// Additive (Bahdanau) attention, fused single-pass over encoder_outputs.
// enc: (32, 8192, 256) fp32 is the only big tensor (256 MiB) -> read ONCE.
// Pipeline:
//   prep:   B16frag = f16(We^T) in MFMA-fragment order (128 KiB), qb[b,k] = b[k] + hidden[b]·Wh[k,:]
//   main:   per block = 256 rows of one batch: MFMA f16 GEMM (enc·We^T) -> +qb -> tanh -> ·v -> logits
//           local softmax stats (m,l) + unnormalized partial context from register-resident enc
//   finish: merge 32 chunks/batch -> context (32x256) and attn weights (32x8192)

typedef _Float16 f16x8 __attribute__((ext_vector_type(8)));
typedef float    f32x4 __attribute__((ext_vector_type(4)));

__device__ __forceinline__ float fast_tanh(float x){
  x = fminf(15.f, fmaxf(-15.f, x));
  float e = __expf(2.f * x);
  return (e - 1.f) * __builtin_amdgcn_rcpf(e + 1.f);
}

// ---------------- prep ----------------
// blocks 0..255: B16frag[tid] for tid=(((nt*8+kc)*64+lane)*8+j)
//   = (f16) W[(nt*16 + (lane&15))*512 + 256 + kc*32 + (lane>>4)*8 + j]
// blocks 256..287: qb[b,k] = bias[k] + sum_h hidden[b,h]*W[k,h]
__global__ void prep_kernel(const float* __restrict__ hidden, const float* __restrict__ W,
                            const float* __restrict__ bias, _Float16* __restrict__ Bfrag,
                            float* __restrict__ qb)
{
  int blk = blockIdx.x;
  if (blk < 256){
    int tid  = blk * 256 + threadIdx.x;      // 0..65535
    int j    = tid & 7;
    int lane = (tid >> 3) & 63;
    int kc   = (tid >> 9) & 7;
    int nt   = tid >> 12;
    int lc   = lane & 15, q = lane >> 4;
    int row  = nt * 16 + lc;                 // output-k index (B's n)
    int col  = 256 + kc * 32 + q * 8 + j;    // W column (h + 256)
    Bfrag[tid] = (_Float16)W[row * 512 + col];
  } else {
    int b = blk - 256;
    int k = threadIdx.x;
    const float4* hp = (const float4*)(hidden + b * 256);
    const float4* wp = (const float4*)(W + k * 512);
    float s = 0.f;
    for (int i = 0; i < 64; i++){
      float4 h4 = hp[i], w4 = wp[i];
      s += h4.x * w4.x + h4.y * w4.y + h4.z * w4.z + h4.w * w4.w;
    }
    qb[b * 256 + k] = s + bias[k];
  }
}

// ---------------- main ----------------
// grid = 1024 (32 b x 32 chunks), block = 512 (8 waves x 32 rows = 256 rows/block)
__global__ __launch_bounds__(512, 4) void attn_main(
    const float* __restrict__ enc, const _Float16* __restrict__ Bfrag,
    const float* __restrict__ qb, const float* __restrict__ v,
    float* __restrict__ logits, float* __restrict__ P,
    float* __restrict__ mw, float* __restrict__ lw)
{
  __shared__ _Float16 Bs[16384];   // one quarter of B (4 n-tiles), 32 KiB
  __shared__ float sl[256];        // logits, then unnormalized weights
  __shared__ float Pl[256];        // partial context accumulator
  __shared__ float red[16];

  const int b = blockIdx.x >> 5, chunk = blockIdx.x & 31;
  const int tid = threadIdx.x, wv = tid >> 6, lane = tid & 63;
  const int q = lane >> 4, lc = lane & 15;
  const int rowBase = b * 8192 + chunk * 256;
  const int waveRow = wv * 32;

  if (tid < 256) Pl[tid] = 0.f;

  // Load this wave's 32 enc rows as f16 A-fragments (register resident, 64 VGPRs).
  // A[m = lane&15][k = (lane>>4)*8 + j], k-chunk kc covers k in [kc*32, kc*32+32).
  f16x8 A[2][8];
  #pragma unroll
  for (int mt = 0; mt < 2; mt++){
    const float* rp = enc + (size_t)(rowBase + waveRow + mt * 16 + lc) * 256 + q * 8;
    #pragma unroll
    for (int kc = 0; kc < 8; kc++){
      const float4* p = (const float4*)(rp + kc * 32);
      float4 x0 = p[0], x1 = p[1];
      f16x8 af;
      af[0] = (_Float16)x0.x; af[1] = (_Float16)x0.y; af[2] = (_Float16)x0.z; af[3] = (_Float16)x0.w;
      af[4] = (_Float16)x1.x; af[5] = (_Float16)x1.y; af[6] = (_Float16)x1.z; af[7] = (_Float16)x1.w;
      A[mt][kc] = af;
    }
  }

  float plog[2][4] = {{0,0,0,0},{0,0,0,0}};
  const float* qbB = qb + b * 256;

  for (int h = 0; h < 4; h++){
    __syncthreads();
    { // stage B quarter (n-tiles h*4 .. h*4+3) into LDS, fragment order
      const f16x8* src = (const f16x8*)(Bfrag + h * 16384);
      f16x8* dst = (f16x8*)Bs;
      for (int i = tid; i < 2048; i += 512) dst[i] = src[i];
    }
    __syncthreads();
    #pragma unroll
    for (int ntl = 0; ntl < 4; ntl++){
      const int nt = h * 4 + ntl;
      f32x4 acc0 = {0,0,0,0}, acc1 = {0,0,0,0};
      const f16x8* bp = ((const f16x8*)Bs) + ntl * 512 + lane;
      #pragma unroll
      for (int kc = 0; kc < 8; kc++){
        f16x8 bf = bp[kc * 64];
        acc0 = __builtin_amdgcn_mfma_f32_16x16x32_f16(A[0][kc], bf, acc0, 0, 0, 0);
        acc1 = __builtin_amdgcn_mfma_f32_16x16x32_f16(A[1][kc], bf, acc1, 0, 0, 0);
      }
      // C/D: col = lane&15 (+nt*16), row = (lane>>4)*4 + r
      const int col = nt * 16 + lc;
      const float qv = qbB[col], vv = v[col];
      #pragma unroll
      for (int r = 0; r < 4; r++){
        plog[0][r] += fast_tanh(acc0[r] + qv) * vv;
        plog[1][r] += fast_tanh(acc1[r] + qv) * vv;
      }
    }
  }

  // reduce logit partials across the 16 columns (lanes sharing q)
  #pragma unroll
  for (int mt = 0; mt < 2; mt++)
    #pragma unroll
    for (int r = 0; r < 4; r++){
      float s = plog[mt][r];
      s += __shfl_xor(s, 1); s += __shfl_xor(s, 2);
      s += __shfl_xor(s, 4); s += __shfl_xor(s, 8);
      plog[mt][r] = s;
    }
  if (lc == 0){
    #pragma unroll
    for (int mt = 0; mt < 2; mt++)
      #pragma unroll
      for (int r = 0; r < 4; r++){
        int rl = waveRow + mt * 16 + q * 4 + r;
        sl[rl] = plog[mt][r];
        logits[rowBase + rl] = plog[mt][r];
      }
  }
  __syncthreads();

  // block-local softmax stats over the 256 logits
  if (tid < 256){
    float x = sl[tid], m = x;
    for (int o = 1; o < 64; o <<= 1) m = fmaxf(m, __shfl_xor(m, o));
    if (lane == 0) red[wv] = m;
  }
  __syncthreads();
  if (tid == 0) red[8] = fmaxf(fmaxf(red[0], red[1]), fmaxf(red[2], red[3]));
  __syncthreads();
  const float M = red[8];
  if (tid < 256){
    float e = __expf(sl[tid] - M);
    sl[tid] = e;                       // unnormalized weight
    float s2 = e;
    for (int o = 1; o < 64; o <<= 1) s2 += __shfl_xor(s2, o);
    if (lane == 0) red[wv] = s2;
  }
  __syncthreads();
  if (tid == 0){ mw[blockIdx.x] = M; lw[blockIdx.x] = red[0] + red[1] + red[2] + red[3]; }

  // partial context from register-resident enc rows: Pl[k] = sum_rows w[row]*enc[row,k]
  const float w0 = sl[waveRow + lc];
  const float w1 = sl[waveRow + 16 + lc];
  #pragma unroll
  for (int kc = 0; kc < 8; kc++){
    float c8[8];
    #pragma unroll
    for (int j = 0; j < 8; j++)
      c8[j] = w0 * (float)A[0][kc][j] + w1 * (float)A[1][kc][j];
    #pragma unroll
    for (int j = 0; j < 8; j++){
      float s = c8[j];
      s += __shfl_xor(s, 1); s += __shfl_xor(s, 2);
      s += __shfl_xor(s, 4); s += __shfl_xor(s, 8);
      c8[j] = s;
    }
    if (lc == 0){
      #pragma unroll
      for (int j = 0; j < 8; j++) atomicAdd(&Pl[kc * 32 + q * 8 + j], c8[j]);
    }
  }
  __syncthreads();
  if (tid < 256) P[(size_t)blockIdx.x * 256 + tid] = Pl[tid];
}

// ---------------- finish ----------------
// grid = 32 (one per batch), block = 256
__global__ void attn_finish(const float* __restrict__ logits, const float* __restrict__ P,
                            const float* __restrict__ mw, const float* __restrict__ lw,
                            float* __restrict__ out)
{
  const int b = blockIdx.x, t = threadIdx.x;
  __shared__ float sm[32], sw[32];
  if (t < 32){ sm[t] = mw[b * 32 + t]; sw[t] = lw[b * 32 + t]; }
  __syncthreads();
  float M = -1e30f;
  for (int i = 0; i < 32; i++) M = fmaxf(M, sm[i]);
  float L = 0.f;
  for (int i = 0; i < 32; i++) L += sw[i] * __expf(sm[i] - M);
  const float inv = 1.f / L;
  // context (t = k index)
  float c = 0.f;
  for (int ch = 0; ch < 32; ch++) c += __expf(sm[ch] - M) * P[(size_t)(b * 32 + ch) * 256 + t];
  out[b * 256 + t] = c * inv;
  // attention weights
  const float* lg = logits + (size_t)b * 8192;
  float* ao = out + 8192 + (size_t)b * 8192;
  for (int s = t; s < 8192; s += 256) ao[s] = __expf(lg[s] - M) * inv;
}

extern "C" void kernel_launch(void* const* d_in, const int* in_sizes, int n_in,
                              void* d_out, int out_size, void* d_ws, size_t ws_size,
                              hipStream_t stream)
{
  const float* hidden = (const float*)d_in[0];   // (1,32,256)
  const float* enc    = (const float*)d_in[1];   // (32,8192,256)
  const float* W      = (const float*)d_in[2];   // (256,512)
  const float* bias   = (const float*)d_in[3];   // (256,)
  const float* v      = (const float*)d_in[4];   // (256,)
  float* out = (float*)d_out;

  char* ws = (char*)d_ws;
  _Float16* Bfrag = (_Float16*)ws;                                   // 131072 B
  float* qb     = (float*)(ws + 131072);                             // 32768 B
  float* logits = (float*)(ws + 131072 + 32768);                     // 1 MiB
  float* P      = (float*)(ws + 131072 + 32768 + 1048576);           // 1 MiB
  float* mw     = (float*)(ws + 131072 + 32768 + 2097152);           // 4 KiB
  float* lw     = (float*)(ws + 131072 + 32768 + 2097152 + 4096);    // 4 KiB

  prep_kernel<<<288, 256, 0, stream>>>(hidden, W, bias, Bfrag, qb);
  attn_main<<<1024, 512, 0, stream>>>(enc, Bfrag, qb, v, logits, P, mw, lw);
  attn_finish<<<32, 256, 0, stream>>>(logits, P, mw, lw, out);
}

// Round 2
// 486.601 us; speedup vs baseline: 1.0521x; 1.0521x over previous
//
#include <hip/hip_runtime.h>

// Additive (Bahdanau) attention, fused single-pass over encoder_outputs.
// enc: (32, 8192, 256) fp32 is the only big tensor (256 MiB) -> read ONCE.
// Pipeline:
//   prep:   B16frag = f16(We^T) in MFMA-fragment order (128 KiB), qb[b,k] = b[k] + hidden[b]·Wh[k,:]
//   main:   per block = 256 rows of one batch: MFMA f16 GEMM (enc·We^T) -> +qb -> tanh -> ·v -> logits
//           local softmax stats (m,l) + unnormalized partial context from register-resident enc
//   finish: merge 32 chunks/batch -> context (32x256) and attn weights (32x8192)
//
// R2: __launch_bounds__(512,4) acted as 4 blocks/CU -> 64-VGPR cap -> the 64-VGPR
// A-fragment array spilled to scratch (WRITE_SIZE 268 MB, attn_main 226 us).
// (512,2) caps at >=128 VGPR under either launch_bounds semantics -> no spill.

typedef _Float16 f16x8 __attribute__((ext_vector_type(8)));
typedef float    f32x4 __attribute__((ext_vector_type(4)));

__device__ __forceinline__ float fast_tanh(float x){
  x = fminf(15.f, fmaxf(-15.f, x));
  float e = __expf(2.f * x);
  return (e - 1.f) * __builtin_amdgcn_rcpf(e + 1.f);
}

// ---------------- prep ----------------
__global__ void prep_kernel(const float* __restrict__ hidden, const float* __restrict__ W,
                            const float* __restrict__ bias, _Float16* __restrict__ Bfrag,
                            float* __restrict__ qb)
{
  int blk = blockIdx.x;
  if (blk < 256){
    int tid  = blk * 256 + threadIdx.x;      // 0..65535
    int j    = tid & 7;
    int lane = (tid >> 3) & 63;
    int kc   = (tid >> 9) & 7;
    int nt   = tid >> 12;
    int lc   = lane & 15, q = lane >> 4;
    int row  = nt * 16 + lc;                 // output-k index (B's n)
    int col  = 256 + kc * 32 + q * 8 + j;    // W column (h + 256)
    Bfrag[tid] = (_Float16)W[row * 512 + col];
  } else {
    int b = blk - 256;
    int k = threadIdx.x;
    const float4* hp = (const float4*)(hidden + b * 256);
    const float4* wp = (const float4*)(W + k * 512);
    float s = 0.f;
    for (int i = 0; i < 64; i++){
      float4 h4 = hp[i], w4 = wp[i];
      s += h4.x * w4.x + h4.y * w4.y + h4.z * w4.z + h4.w * w4.w;
    }
    qb[b * 256 + k] = s + bias[k];
  }
}

// ---------------- main ----------------
// grid = 1024 (32 b x 32 chunks), block = 512 (8 waves x 32 rows = 256 rows/block)
__global__ __launch_bounds__(512, 2) void attn_main(
    const float* __restrict__ enc, const _Float16* __restrict__ Bfrag,
    const float* __restrict__ qb, const float* __restrict__ v,
    float* __restrict__ logits, float* __restrict__ P,
    float* __restrict__ mw, float* __restrict__ lw)
{
  __shared__ _Float16 Bs[16384];   // one quarter of B (4 n-tiles), 32 KiB
  __shared__ float sl[256];        // logits, then unnormalized weights
  __shared__ float Pl[256];        // partial context accumulator
  __shared__ float red[16];

  const int b = blockIdx.x >> 5, chunk = blockIdx.x & 31;
  const int tid = threadIdx.x, wv = tid >> 6, lane = tid & 63;
  const int q = lane >> 4, lc = lane & 15;
  const int rowBase = b * 8192 + chunk * 256;
  const int waveRow = wv * 32;

  if (tid < 256) Pl[tid] = 0.f;

  // Load this wave's 32 enc rows as f16 A-fragments (register resident, 64 VGPRs).
  // A[m = lane&15][k = (lane>>4)*8 + j], k-chunk kc covers k in [kc*32, kc*32+32).
  f16x8 A[2][8];
  #pragma unroll
  for (int mt = 0; mt < 2; mt++){
    const float* rp = enc + (size_t)(rowBase + waveRow + mt * 16 + lc) * 256 + q * 8;
    #pragma unroll
    for (int kc = 0; kc < 8; kc++){
      const float4* p = (const float4*)(rp + kc * 32);
      float4 x0 = p[0], x1 = p[1];
      f16x8 af;
      af[0] = (_Float16)x0.x; af[1] = (_Float16)x0.y; af[2] = (_Float16)x0.z; af[3] = (_Float16)x0.w;
      af[4] = (_Float16)x1.x; af[5] = (_Float16)x1.y; af[6] = (_Float16)x1.z; af[7] = (_Float16)x1.w;
      A[mt][kc] = af;
    }
  }

  float plog[2][4] = {{0,0,0,0},{0,0,0,0}};
  const float* qbB = qb + b * 256;

  for (int h = 0; h < 4; h++){
    __syncthreads();
    { // stage B quarter (n-tiles h*4 .. h*4+3) into LDS, fragment order
      const f16x8* src = (const f16x8*)(Bfrag + h * 16384);
      f16x8* dst = (f16x8*)Bs;
      for (int i = tid; i < 2048; i += 512) dst[i] = src[i];
    }
    __syncthreads();
    #pragma unroll
    for (int ntl = 0; ntl < 4; ntl++){
      const int nt = h * 4 + ntl;
      f32x4 acc0 = {0,0,0,0}, acc1 = {0,0,0,0};
      const f16x8* bp = ((const f16x8*)Bs) + ntl * 512 + lane;
      #pragma unroll
      for (int kc = 0; kc < 8; kc++){
        f16x8 bf = bp[kc * 64];
        acc0 = __builtin_amdgcn_mfma_f32_16x16x32_f16(A[0][kc], bf, acc0, 0, 0, 0);
        acc1 = __builtin_amdgcn_mfma_f32_16x16x32_f16(A[1][kc], bf, acc1, 0, 0, 0);
      }
      // C/D: col = lane&15 (+nt*16), row = (lane>>4)*4 + r
      const int col = nt * 16 + lc;
      const float qv = qbB[col], vv = v[col];
      #pragma unroll
      for (int r = 0; r < 4; r++){
        plog[0][r] += fast_tanh(acc0[r] + qv) * vv;
        plog[1][r] += fast_tanh(acc1[r] + qv) * vv;
      }
    }
  }

  // reduce logit partials across the 16 columns (lanes sharing q)
  #pragma unroll
  for (int mt = 0; mt < 2; mt++)
    #pragma unroll
    for (int r = 0; r < 4; r++){
      float s = plog[mt][r];
      s += __shfl_xor(s, 1); s += __shfl_xor(s, 2);
      s += __shfl_xor(s, 4); s += __shfl_xor(s, 8);
      plog[mt][r] = s;
    }
  if (lc == 0){
    #pragma unroll
    for (int mt = 0; mt < 2; mt++)
      #pragma unroll
      for (int r = 0; r < 4; r++){
        int rl = waveRow + mt * 16 + q * 4 + r;
        sl[rl] = plog[mt][r];
        logits[rowBase + rl] = plog[mt][r];
      }
  }
  __syncthreads();

  // block-local softmax stats over the 256 logits
  if (tid < 256){
    float x = sl[tid], m = x;
    for (int o = 1; o < 64; o <<= 1) m = fmaxf(m, __shfl_xor(m, o));
    if (lane == 0) red[wv] = m;
  }
  __syncthreads();
  if (tid == 0) red[8] = fmaxf(fmaxf(red[0], red[1]), fmaxf(red[2], red[3]));
  __syncthreads();
  const float M = red[8];
  if (tid < 256){
    float e = __expf(sl[tid] - M);
    sl[tid] = e;                       // unnormalized weight
    float s2 = e;
    for (int o = 1; o < 64; o <<= 1) s2 += __shfl_xor(s2, o);
    if (lane == 0) red[wv] = s2;
  }
  __syncthreads();
  if (tid == 0){ mw[blockIdx.x] = M; lw[blockIdx.x] = red[0] + red[1] + red[2] + red[3]; }

  // partial context from register-resident enc rows: Pl[k] = sum_rows w[row]*enc[row,k]
  const float w0 = sl[waveRow + lc];
  const float w1 = sl[waveRow + 16 + lc];
  #pragma unroll
  for (int kc = 0; kc < 8; kc++){
    float c8[8];
    #pragma unroll
    for (int j = 0; j < 8; j++)
      c8[j] = w0 * (float)A[0][kc][j] + w1 * (float)A[1][kc][j];
    #pragma unroll
    for (int j = 0; j < 8; j++){
      float s = c8[j];
      s += __shfl_xor(s, 1); s += __shfl_xor(s, 2);
      s += __shfl_xor(s, 4); s += __shfl_xor(s, 8);
      c8[j] = s;
    }
    if (lc == 0){
      #pragma unroll
      for (int j = 0; j < 8; j++) atomicAdd(&Pl[kc * 32 + q * 8 + j], c8[j]);
    }
  }
  __syncthreads();
  if (tid < 256) P[(size_t)blockIdx.x * 256 + tid] = Pl[tid];
}

// ---------------- finish ----------------
// grid = 32 (one per batch), block = 256
__global__ void attn_finish(const float* __restrict__ logits, const float* __restrict__ P,
                            const float* __restrict__ mw, const float* __restrict__ lw,
                            float* __restrict__ out)
{
  const int b = blockIdx.x, t = threadIdx.x;
  __shared__ float sm[32], sw[32];
  if (t < 32){ sm[t] = mw[b * 32 + t]; sw[t] = lw[b * 32 + t]; }
  __syncthreads();
  float M = -1e30f;
  for (int i = 0; i < 32; i++) M = fmaxf(M, sm[i]);
  float L = 0.f;
  for (int i = 0; i < 32; i++) L += sw[i] * __expf(sm[i] - M);
  const float inv = 1.f / L;
  // context (t = k index)
  float c = 0.f;
  for (int ch = 0; ch < 32; ch++) c += __expf(sm[ch] - M) * P[(size_t)(b * 32 + ch) * 256 + t];
  out[b * 256 + t] = c * inv;
  // attention weights
  const float* lg = logits + (size_t)b * 8192;
  float* ao = out + 8192 + (size_t)b * 8192;
  for (int s = t; s < 8192; s += 256) ao[s] = __expf(lg[s] - M) * inv;
}

extern "C" void kernel_launch(void* const* d_in, const int* in_sizes, int n_in,
                              void* d_out, int out_size, void* d_ws, size_t ws_size,
                              hipStream_t stream)
{
  const float* hidden = (const float*)d_in[0];   // (1,32,256)
  const float* enc    = (const float*)d_in[1];   // (32,8192,256)
  const float* W      = (const float*)d_in[2];   // (256,512)
  const float* bias   = (const float*)d_in[3];   // (256,)
  const float* v      = (const float*)d_in[4];   // (256,)
  float* out = (float*)d_out;

  char* ws = (char*)d_ws;
  _Float16* Bfrag = (_Float16*)ws;                                   // 131072 B
  float* qb     = (float*)(ws + 131072);                             // 32768 B
  float* logits = (float*)(ws + 131072 + 32768);                     // 1 MiB
  float* P      = (float*)(ws + 131072 + 32768 + 1048576);           // 1 MiB
  float* mw     = (float*)(ws + 131072 + 32768 + 2097152);           // 4 KiB
  float* lw     = (float*)(ws + 131072 + 32768 + 2097152 + 4096);    // 4 KiB

  prep_kernel<<<288, 256, 0, stream>>>(hidden, W, bias, Bfrag, qb);
  attn_main<<<1024, 512, 0, stream>>>(enc, Bfrag, qb, v, logits, P, mw, lw);
  attn_finish<<<32, 256, 0, stream>>>(logits, P, mw, lw, out);
}